// Round 7
// baseline (869.479 us; speedup 1.0000x reference)
//
#include <hip/hip_runtime.h>
#include <hip/hip_bf16.h>

// ---------------- problem constants ----------------
constexpr int Nres = 512;
constexpr int Cs   = 384;
constexpr int Cz   = 128;
constexpr int NH   = 12;
constexpr int HC   = 16;
constexpr int NPQ  = 4;
constexpr int NPV  = 8;
constexpr int NBLK = 8;
constexpr int PROJD = NH*HC + NH*2*HC + NH*NPQ*3 + NH*(NPQ+NPV)*3; // 1152
constexpr int CATD = NH*HC + NH*NPV*3 + NH*NPV + NH*Cz;            // 2112
constexpr float W_L  = 0.57735026918962576f;  // sqrt(1/3)
constexpr float W_C2 = 0.11785113019775793f;  // sqrt(2/(9*PQ)) / 2

using u16 = unsigned short;
typedef __bf16 bf16x8 __attribute__((ext_vector_type(8)));
typedef float  f32x4  __attribute__((ext_vector_type(4)));

static inline int gdiv(int n, int b) { return (n + b - 1) / b; }

static __device__ __forceinline__ u16 f2bf(float x) {
    __hip_bfloat16 h = __float2bfloat16(x);
    return *reinterpret_cast<u16*>(&h);
}
static __device__ __forceinline__ float bf2f(u16 x) {
    return __bfloat162float(*reinterpret_cast<__hip_bfloat16*>(&x));
}

// ---------------- init ----------------
__global__ void k_init(const float* __restrict__ s_in, float* __restrict__ s_cur,
                       u16* __restrict__ s_bf,
                       float* __restrict__ R, float* __restrict__ t) {
    int idx = blockIdx.x * blockDim.x + threadIdx.x;
    if (idx < Nres * Cs) { float v = s_in[idx]; s_cur[idx] = v; s_bf[idx] = f2bf(v); }
    if (idx < Nres * 9) {
        int e = idx % 9;
        R[idx] = (e == 0 || e == 4 || e == 8) ? 1.f : 0.f;
    }
    if (idx < Nres * 3) t[idx] = 0.f;
}

// concat projection weights into Wcat[384][1152] (fp32 staging for transpose)
__global__ void k_concatW(const float* __restrict__ w_q, const float* __restrict__ w_kv,
                          const float* __restrict__ w_qpts, const float* __restrict__ w_kvpts,
                          float* __restrict__ Wcat) {
    int idx = blockIdx.x * blockDim.x + threadIdx.x;
    if (idx >= Cs * PROJD) return;
    int k = idx / PROJD, n = idx - k * PROJD;
    float v;
    if      (n < 192) v = w_q[k * 192 + n];
    else if (n < 576) v = w_kv[k * 384 + (n - 192)];
    else if (n < 720) v = w_qpts[k * 144 + (n - 576)];
    else              v = w_kvpts[k * 432 + (n - 720)];
    Wcat[idx] = v;
}

// transpose + bf16 convert: out[n][k] = in[k][n]; K,N multiples of 32
__global__ void k_transposeW(const float* __restrict__ in, u16* __restrict__ out,
                             int K, int N) {
    __shared__ float tile[32][33];
    int n0 = blockIdx.x * 32, k0 = blockIdx.y * 32;
    int tx = threadIdx.x & 31, ty = threadIdx.x >> 5;   // ty 0..7
#pragma unroll
    for (int j = 0; j < 4; j++)
        tile[ty + j * 8][tx] = in[(size_t)(k0 + ty + j * 8) * N + n0 + tx];
    __syncthreads();
#pragma unroll
    for (int j = 0; j < 4; j++)
        out[(size_t)(n0 + ty + j * 8) * K + k0 + tx] = f2bf(tile[tx][ty + j * 8]);
}

// one-time: z[i][j][c] fp32 -> zT[i][c][j] bf16
__global__ void k_zT(const float* __restrict__ z, u16* __restrict__ zT) {
    __shared__ float tile[32][33];
    int i  = blockIdx.x;
    int j0 = blockIdx.y * 32;
    int c0 = blockIdx.z * 32;
    int tx = threadIdx.x & 31, ty = threadIdx.x >> 5;   // ty 0..7
    const float* src = z + (size_t)i * Nres * Cz;
#pragma unroll
    for (int l = 0; l < 4; l++)
        tile[ty + l * 8][tx] = src[(size_t)(j0 + ty + l * 8) * Cz + c0 + tx];
    __syncthreads();
    u16* dst = zT + (size_t)i * Cz * Nres;
#pragma unroll
    for (int l = 0; l < 4; l++)
        dst[(size_t)(c0 + ty + l * 8) * Nres + j0 + tx] = f2bf(tile[tx][ty + l * 8]);
}

// ---------------- proj GEMM: split-K=2, 32x64 tile, dbuf, TRANSPOSED fp32 slab out ----------------
// slab z: outT[z][n][m] = partial (A @ Bt^T)[m][n] over k in [z*192, z*192+192)
__global__ void __launch_bounds__(256)
k_gemm_proj(const u16* __restrict__ A, const u16* __restrict__ Bt,
            float* __restrict__ outT, int M, int K, int N) {
    __shared__ u16 As[2][32 * 40];
    __shared__ u16 Bs[2][64 * 40];
    const int tid = threadIdx.x;
    const int m0 = blockIdx.y * 32;
    const int n0 = blockIdx.x * 64;
    const int kbeg = blockIdx.z * 192;
    const int kend = kbeg + 192;
    const int wv = tid >> 6, lane = tid & 63;
    const int wm = (wv >> 1) * 16, wn = (wv & 1) * 32;
    const int lrow = lane & 15, lq = lane >> 4;
    f32x4 zero = {0.f, 0.f, 0.f, 0.f};
    f32x4 acc0 = zero, acc1 = zero;
    const int srow = tid >> 2, sko = (tid & 3) * 8;
    const size_t aoff = (size_t)(m0 + srow) * K + sko;   // valid for tid<128
    const size_t boff = (size_t)(n0 + srow) * K + sko;

    uint4 ra, rb;
    if (tid < 128) ra = *(const uint4*)&A[aoff + kbeg];
    rb = *(const uint4*)&Bt[boff + kbeg];
    if (tid < 128) *(uint4*)&As[0][srow * 40 + sko] = ra;
    *(uint4*)&Bs[0][srow * 40 + sko] = rb;
    __syncthreads();

    int buf = 0;
    for (int k0 = kbeg; k0 < kend; k0 += 32) {
        const bool nxt = (k0 + 32 < kend);
        if (nxt) {
            if (tid < 128) ra = *(const uint4*)&A[aoff + k0 + 32];
            rb = *(const uint4*)&Bt[boff + k0 + 32];
        }
        bf16x8 a  = *reinterpret_cast<const bf16x8*>(&As[buf][(wm + lrow) * 40 + lq * 8]);
        bf16x8 b0 = *reinterpret_cast<const bf16x8*>(&Bs[buf][(wn + lrow) * 40 + lq * 8]);
        bf16x8 b1 = *reinterpret_cast<const bf16x8*>(&Bs[buf][(wn + 16 + lrow) * 40 + lq * 8]);
        acc0 = __builtin_amdgcn_mfma_f32_16x16x32_bf16(a, b0, acc0, 0, 0, 0);
        acc1 = __builtin_amdgcn_mfma_f32_16x16x32_bf16(a, b1, acc1, 0, 0, 0);
        if (nxt) {
            if (tid < 128) *(uint4*)&As[buf ^ 1][srow * 40 + sko] = ra;
            *(uint4*)&Bs[buf ^ 1][srow * 40 + sko] = rb;
            __syncthreads();
            buf ^= 1;
        }
    }
    float* op = outT + (size_t)blockIdx.z * N * M;
    const int rbase = m0 + wm + lq * 4;
    const int cbase = n0 + wn + lrow;
    *reinterpret_cast<f32x4*>(&op[(size_t)cbase * M + rbase])        = acc0;
    *reinterpret_cast<f32x4*>(&op[(size_t)(cbase + 16) * M + rbase]) = acc1;
}

// ---------------- unified split-K GEMM, 32x64 tile, dbuf ----------------
// A-side: bf16 Abf [M][K], or fp32 relu(sum of 4 slabs) Aslab (K=Cs).
// grid (N/64=6, Nres/32, nsplit). Pout slab z at z*Nres*Cs.
__global__ void __launch_bounds__(256)
k_gemm_sk(const u16* __restrict__ Abf, const float* __restrict__ Aslab,
          const u16* __restrict__ Bt, float* __restrict__ Pout,
          int K, int Kc) {
    __shared__ u16 Asm[2][32 * 40];
    __shared__ u16 Bsm[2][64 * 40];
    const int tid = threadIdx.x;
    const int m0 = blockIdx.y * 32;
    const int n0 = blockIdx.x * 64;
    const int kbeg = blockIdx.z * Kc;
    const int kend = kbeg + Kc;
    const int wv = tid >> 6, lane = tid & 63;
    const int wm = (wv >> 1) * 16, wn = (wv & 1) * 32;
    const int lrow = lane & 15, lq = lane >> 4;
    f32x4 zero = {0.f, 0.f, 0.f, 0.f};
    f32x4 acc0 = zero, acc1 = zero;
    const int srow = tid >> 2, sko = (tid & 3) * 8;     // bf16-A + B side
    const int rowR = tid >> 3, c4 = (tid & 7) * 4;      // fp32-slab A side
    const size_t aoffb = (size_t)(m0 + srow) * K + sko;
    const size_t aoffr = (size_t)(m0 + rowR) * K + c4;
    const size_t boff  = (size_t)(n0 + srow) * K + sko;
    constexpr size_t SL = (size_t)Nres * Cs;

    uint4 ra, rb;
    float4 f0, f1, f2, f3;
    rb = *(const uint4*)&Bt[boff + kbeg];
    if (Aslab == nullptr) { if (tid < 128) ra = *(const uint4*)&Abf[aoffb + kbeg]; }
    else {
        f0 = *(const float4*)&Aslab[aoffr + kbeg];
        f1 = *(const float4*)&Aslab[SL + aoffr + kbeg];
        f2 = *(const float4*)&Aslab[2*SL + aoffr + kbeg];
        f3 = *(const float4*)&Aslab[3*SL + aoffr + kbeg];
    }

#define STAGE_A(b)                                                              \
    if (Aslab == nullptr) {                                                     \
        if (tid < 128) *(uint4*)&Asm[b][srow * 40 + sko] = ra;                  \
    } else {                                                                    \
        float x0 = fmaxf(f0.x + f1.x + f2.x + f3.x, 0.f);                       \
        float x1 = fmaxf(f0.y + f1.y + f2.y + f3.y, 0.f);                       \
        float x2 = fmaxf(f0.z + f1.z + f2.z + f3.z, 0.f);                       \
        float x3 = fmaxf(f0.w + f1.w + f2.w + f3.w, 0.f);                       \
        uint2 wp;                                                               \
        wp.x = (unsigned)f2bf(x0) | ((unsigned)f2bf(x1) << 16);                 \
        wp.y = (unsigned)f2bf(x2) | ((unsigned)f2bf(x3) << 16);                 \
        *(uint2*)&Asm[b][rowR * 40 + c4] = wp;                                  \
    }

    STAGE_A(0);
    *(uint4*)&Bsm[0][srow * 40 + sko] = rb;
    __syncthreads();

    int buf = 0;
    for (int k0 = kbeg; k0 < kend; k0 += 32) {
        const bool nxt = (k0 + 32 < kend);
        if (nxt) {
            rb = *(const uint4*)&Bt[boff + k0 + 32];
            if (Aslab == nullptr) { if (tid < 128) ra = *(const uint4*)&Abf[aoffb + k0 + 32]; }
            else {
                f0 = *(const float4*)&Aslab[aoffr + k0 + 32];
                f1 = *(const float4*)&Aslab[SL + aoffr + k0 + 32];
                f2 = *(const float4*)&Aslab[2*SL + aoffr + k0 + 32];
                f3 = *(const float4*)&Aslab[3*SL + aoffr + k0 + 32];
            }
        }
        bf16x8 a  = *reinterpret_cast<const bf16x8*>(&Asm[buf][(wm + lrow) * 40 + lq * 8]);
        bf16x8 b0 = *reinterpret_cast<const bf16x8*>(&Bsm[buf][(wn + lrow) * 40 + lq * 8]);
        bf16x8 b1 = *reinterpret_cast<const bf16x8*>(&Bsm[buf][(wn + 16 + lrow) * 40 + lq * 8]);
        acc0 = __builtin_amdgcn_mfma_f32_16x16x32_bf16(a, b0, acc0, 0, 0, 0);
        acc1 = __builtin_amdgcn_mfma_f32_16x16x32_bf16(a, b1, acc1, 0, 0, 0);
        if (nxt) {
            STAGE_A(buf ^ 1);
            *(uint4*)&Bsm[buf ^ 1][srow * 40 + sko] = rb;
            __syncthreads();
            buf ^= 1;
        }
    }
#undef STAGE_A
    float* Pp = Pout + (size_t)blockIdx.z * SL;
    const int rbase = m0 + wm + lq * 4;
    const int cbase = n0 + wn + lrow;
#pragma unroll
    for (int r = 0; r < 4; r++) {
        Pp[(size_t)(rbase + r) * Cs + cbase]      = acc0[r];
        Pp[(size_t)(rbase + r) * Cs + cbase + 16] = acc1[r];
    }
}

// ---------------- b_hij (once), pre-scaled by W_L, bf16 out ----------------
__global__ void k_bproj(const float* __restrict__ z, const float* __restrict__ w_b,
                        u16* __restrict__ b_hij_bf) {
    __shared__ float zs[16][129];
    __shared__ float wbs[Cz * NH];
    const int tid = threadIdx.x;
    const int base = blockIdx.x * 16;
#pragma unroll
    for (int l = 0; l < 6; l++) {
        int idx = tid + l * 256;
        if (idx < Cz * NH) wbs[idx] = w_b[idx];
    }
#pragma unroll
    for (int l = 0; l < 8; l++) {
        int idx = tid + l * 256;
        int r = idx >> 7, c = idx & 127;
        zs[r][c] = z[(size_t)(base + r) * Cz + c];
    }
    __syncthreads();
    if (tid < 192) {
        int h = tid >> 4, r = tid & 15;
        float acc = 0.f;
        for (int c = 0; c < Cz; c++) acc += zs[r][c] * wbs[c * NH + h];
        int row = base + r;
        int i = row >> 9, j = row & 511;
        b_hij_bf[((size_t)h * Nres + i) * Nres + j] = f2bf(acc * W_L);
    }
}

// ---------------- prep: build Aaug/Baug + vhT from projT slabs (coalesced, 2-slab sum) ----------------
__global__ void k_prep(const float* __restrict__ projT, const float* __restrict__ R,
                       const float* __restrict__ t, const float* __restrict__ hw,
                       u16* __restrict__ Aaug, u16* __restrict__ Baug,
                       u16* __restrict__ vhT) {
    int idx = blockIdx.x * blockDim.x + threadIdx.x;
    if (idx >= NH * Nres) return;
    int h = idx / Nres, i = idx % Nres;
    constexpr size_t PSL = (size_t)PROJD * Nres;
#define PR(col) (projT[(size_t)(col) * Nres + i] + projT[PSL + (size_t)(col) * Nres + i])
    float R_[9], t_[3];
#pragma unroll
    for (int e = 0; e < 9; e++) R_[e] = R[i * 9 + e];
#pragma unroll
    for (int e = 0; e < 3; e++) t_[e] = t[i * 3 + e];
    float gam = log1pf(__expf(hw[h]));
    float ch  = sqrtf(2.f * gam * W_C2);

    u16 arow[32], brow[32];
#pragma unroll
    for (int c = 0; c < HC; c++) {
        arow[c] = f2bf(PR(h * HC + c) * (W_L * 0.25f));
        brow[c] = f2bf(PR(192 + h * 2 * HC + c));
        vhT[((size_t)h * 48 + c) * Nres + i] = f2bf(PR(192 + h * 2 * HC + HC + c));
    }
#pragma unroll
    for (int p = 0; p < NPQ; p++) {
        int c0 = 576 + (h * NPQ + p) * 3;
        float y0 = PR(c0 + 0), y1 = PR(c0 + 1), y2 = PR(c0 + 2);
        float v0 = R_[0]*y0 + R_[1]*y1 + R_[2]*y2 + t_[0];
        float v1 = R_[3]*y0 + R_[4]*y1 + R_[5]*y2 + t_[1];
        float v2 = R_[6]*y0 + R_[7]*y1 + R_[8]*y2 + t_[2];
        float s = W_L * ch;
        arow[16 + p*3 + 0] = f2bf(v0 * s);
        arow[16 + p*3 + 1] = f2bf(v1 * s);
        arow[16 + p*3 + 2] = f2bf(v2 * s);
    }
    float sk = 0.f;
#pragma unroll
    for (int p = 0; p < NPQ + NPV; p++) {
        int c0 = 720 + (h * (NPQ+NPV) + p) * 3;
        float y0 = PR(c0 + 0), y1 = PR(c0 + 1), y2 = PR(c0 + 2);
        float v0 = R_[0]*y0 + R_[1]*y1 + R_[2]*y2 + t_[0];
        float v1 = R_[3]*y0 + R_[4]*y1 + R_[5]*y2 + t_[1];
        float v2 = R_[6]*y0 + R_[7]*y1 + R_[8]*y2 + t_[2];
        if (p < NPQ) {
            brow[16 + p*3 + 0] = f2bf(v0 * ch);
            brow[16 + p*3 + 1] = f2bf(v1 * ch);
            brow[16 + p*3 + 2] = f2bf(v2 * ch);
            sk += v0*v0 + v1*v1 + v2*v2;
        } else {
            int cc = 16 + (p - NPQ) * 3;
            vhT[((size_t)h * 48 + cc + 0) * Nres + i] = f2bf(v0);
            vhT[((size_t)h * 48 + cc + 1) * Nres + i] = f2bf(v1);
            vhT[((size_t)h * 48 + cc + 2) * Nres + i] = f2bf(v2);
        }
    }
#undef PR
    float x = -W_L * gam * W_C2 * sk;
    u16 hi = f2bf(x);
    float lo = x - bf2f(hi);
    arow[28] = f2bf(1.0f); arow[29] = f2bf(1.0f); arow[30] = 0; arow[31] = 0;
    brow[28] = hi;         brow[29] = f2bf(lo);   brow[30] = 0; brow[31] = 0;

    uint4* ad = (uint4*)&Aaug[((size_t)h * Nres + i) * 32];
    uint4* bd = (uint4*)&Baug[((size_t)h * Nres + i) * 32];
    const uint4* as = (const uint4*)arow;
    const uint4* bs = (const uint4*)brow;
#pragma unroll
    for (int e = 0; e < 4; e++) { ad[e] = as[e]; bd[e] = bs[e]; }
}

// ---------------- fused attention v2: 16-row tiles, direct-global fragments ----------------
// grid (Nres/16, NH), 256 threads. Wave w: QK j-quarter w, ov K-quarter w.
__global__ void __launch_bounds__(256)
k_attn(const u16* __restrict__ Aaug, const u16* __restrict__ Baug,
       const u16* __restrict__ b_hij_bf, const u16* __restrict__ vhT,
       const float* __restrict__ R, const float* __restrict__ t,
       u16* __restrict__ Pbf, u16* __restrict__ cat_bf) {
    __shared__ u16 P_lds[16 * 520];       // b_hij staging, then P
    __shared__ float Ctp[4][16 * 49];     // ov partials per wave
    __shared__ float sred[4][32];         // softmax cross-wave

    const int i0 = blockIdx.x * 16;
    const int h  = blockIdx.y;
    const int tid = threadIdx.x;
    const int w = tid >> 6, lane = tid & 63;
    const int lrow = lane & 15, lq = lane >> 4;
    const int jbase = w * 128;

    const u16* bhp = b_hij_bf + ((size_t)h * Nres + i0) * Nres;
    uint4 bhreg[4];
#pragma unroll
    for (int l = 0; l < 4; l++) {
        int v = tid + l * 256;
        int rr = v >> 6, cq = v & 63;
        bhreg[l] = *(const uint4*)&bhp[(size_t)rr * Nres + cq * 8];
    }

    bf16x8 afrag = *reinterpret_cast<const bf16x8*>(
        &Aaug[((size_t)h * Nres + i0 + lrow) * 32 + lq * 8]);
    f32x4 zero = {0.f, 0.f, 0.f, 0.f};
    f32x4 acc[8];
#pragma unroll
    for (int tt = 0; tt < 8; tt++) {
        bf16x8 bfr = *reinterpret_cast<const bf16x8*>(
            &Baug[((size_t)h * Nres + jbase + tt * 16 + lrow) * 32 + lq * 8]);
        acc[tt] = __builtin_amdgcn_mfma_f32_16x16x32_bf16(afrag, bfr, zero, 0, 0, 0);
    }

#pragma unroll
    for (int l = 0; l < 4; l++) {
        int v = tid + l * 256;
        int rr = v >> 6, cq = v & 63;
        *(uint4*)&P_lds[rr * 520 + cq * 8] = bhreg[l];
    }
    __syncthreads();
#pragma unroll
    for (int tt = 0; tt < 8; tt++)
#pragma unroll
        for (int r = 0; r < 4; r++)
            acc[tt][r] += bf2f(P_lds[(lq * 4 + r) * 520 + jbase + tt * 16 + lrow]);

    float pmx[4] = {-1e30f, -1e30f, -1e30f, -1e30f};
#pragma unroll
    for (int tt = 0; tt < 8; tt++)
#pragma unroll
        for (int r = 0; r < 4; r++) pmx[r] = fmaxf(pmx[r], acc[tt][r]);
#pragma unroll
    for (int off = 8; off > 0; off >>= 1)
#pragma unroll
        for (int r = 0; r < 4; r++) pmx[r] = fmaxf(pmx[r], __shfl_xor(pmx[r], off));
    if (lrow == 0) {
#pragma unroll
        for (int r = 0; r < 4; r++) sred[w][lq * 4 + r] = pmx[r];
    }
    __syncthreads();
    float mx[4];
#pragma unroll
    for (int r = 0; r < 4; r++) {
        int row = lq * 4 + r;
        mx[r] = fmaxf(fmaxf(sred[0][row], sred[1][row]), fmaxf(sred[2][row], sred[3][row]));
    }
    float psm[4] = {0.f, 0.f, 0.f, 0.f};
#pragma unroll
    for (int tt = 0; tt < 8; tt++)
#pragma unroll
        for (int r = 0; r < 4; r++) { acc[tt][r] = __expf(acc[tt][r] - mx[r]); psm[r] += acc[tt][r]; }
#pragma unroll
    for (int off = 8; off > 0; off >>= 1)
#pragma unroll
        for (int r = 0; r < 4; r++) psm[r] += __shfl_xor(psm[r], off);
    if (lrow == 0) {
#pragma unroll
        for (int r = 0; r < 4; r++) sred[w][16 + lq * 4 + r] = psm[r];
    }
    __syncthreads();
    float inv[4];
#pragma unroll
    for (int r = 0; r < 4; r++) {
        int row = 16 + lq * 4 + r;
        inv[r] = 1.f / (sred[0][row] + sred[1][row] + sred[2][row] + sred[3][row]);
    }

#pragma unroll
    for (int tt = 0; tt < 8; tt++)
#pragma unroll
        for (int r = 0; r < 4; r++)
            P_lds[(lq * 4 + r) * 520 + jbase + tt * 16 + lrow] = f2bf(acc[tt][r] * inv[r]);
    __syncthreads();

#pragma unroll
    for (int l = 0; l < 4; l++) {
        int v = tid + l * 256;
        int rr = v >> 6, cq = v & 63;
        *(uint4*)&Pbf[((size_t)h * Nres + i0 + rr) * 512 + cq * 8] =
            *(const uint4*)&P_lds[rr * 520 + cq * 8];
    }

    const u16* Bvp = vhT + (size_t)h * 48 * Nres;
    f32x4 o0 = zero, o1 = zero, o2 = zero;
#pragma unroll
    for (int s = 0; s < 4; s++) {
        int k0 = w * 128 + s * 32;
        bf16x8 a  = *reinterpret_cast<const bf16x8*>(&P_lds[lrow * 520 + k0 + lq * 8]);
        bf16x8 b0 = *reinterpret_cast<const bf16x8*>(&Bvp[(size_t)(lrow) * Nres + k0 + lq * 8]);
        bf16x8 b1 = *reinterpret_cast<const bf16x8*>(&Bvp[(size_t)(16 + lrow) * Nres + k0 + lq * 8]);
        bf16x8 b2 = *reinterpret_cast<const bf16x8*>(&Bvp[(size_t)(32 + lrow) * Nres + k0 + lq * 8]);
        o0 = __builtin_amdgcn_mfma_f32_16x16x32_bf16(a, b0, o0, 0, 0, 0);
        o1 = __builtin_amdgcn_mfma_f32_16x16x32_bf16(a, b1, o1, 0, 0, 0);
        o2 = __builtin_amdgcn_mfma_f32_16x16x32_bf16(a, b2, o2, 0, 0, 0);
    }
#pragma unroll
    for (int r = 0; r < 4; r++) {
        int row = lq * 4 + r;
        Ctp[w][row * 49 + lrow]      = o0[r];
        Ctp[w][row * 49 + 16 + lrow] = o1[r];
        Ctp[w][row * 49 + 32 + lrow] = o2[r];
    }
    __syncthreads();

    {
        int r = tid >> 4, c = tid & 15;
        float v = Ctp[0][r * 49 + c] + Ctp[1][r * 49 + c] + Ctp[2][r * 49 + c] + Ctp[3][r * 49 + c];
        cat_bf[(size_t)(i0 + r) * CATD + h * HC + c] = f2bf(v);
    }
    if (tid < 128) {
        int r = tid >> 3, p = tid & 7;
        int i = i0 + r;
        float g0 = 0.f, g1 = 0.f, g2 = 0.f;
#pragma unroll
        for (int ww = 0; ww < 4; ww++) {
            g0 += Ctp[ww][r * 49 + 16 + p * 3 + 0];
            g1 += Ctp[ww][r * 49 + 16 + p * 3 + 1];
            g2 += Ctp[ww][r * 49 + 16 + p * 3 + 2];
        }
        float d0 = g0 - t[i * 3 + 0], d1 = g1 - t[i * 3 + 1], d2v = g2 - t[i * 3 + 2];
        const float* Rn = R + i * 9;
        float l0 = Rn[0] * d0 + Rn[3] * d1 + Rn[6] * d2v;
        float l1 = Rn[1] * d0 + Rn[4] * d1 + Rn[7] * d2v;
        float l2 = Rn[2] * d0 + Rn[5] * d1 + Rn[8] * d2v;
        int hp = h * NPV + p;
        u16* crow = cat_bf + (size_t)i * CATD;
        crow[192 + hp * 3 + 0] = f2bf(l0);
        crow[192 + hp * 3 + 1] = f2bf(l1);
        crow[192 + hp * 3 + 2] = f2bf(l2);
        crow[480 + hp] = f2bf(sqrtf(l0 * l0 + l1 * l1 + l2 * l2 + 1e-8f));
    }
}

// ---------------- o_pair MFMA (reads Pbf), z double-buffered ----------------
__global__ void __launch_bounds__(256)
k_opair(const u16* __restrict__ Pbf, const u16* __restrict__ zT,
        u16* __restrict__ cat_bf) {
    __shared__ u16 P_lds[16 * 520];
    __shared__ u16 Bs[2][128 * 40];
    const int i = blockIdx.x;
    const int tid = threadIdx.x;
    const int wv = tid >> 6, ln = tid & 63;
    const int srow = tid >> 2, sko = (tid & 3) * 8;
    const u16* Bp = zT + (size_t)i * Cz * Nres;
    const size_t b0off = (size_t)srow * Nres + sko;
    const size_t b1off = (size_t)(64 + srow) * Nres + sko;

    uint4 rb0 = *(const uint4*)&Bp[b0off];
    uint4 rb1 = *(const uint4*)&Bp[b1off];

#pragma unroll
    for (int l = 0; l < 3; l++) {
        int v = tid + l * 256;
        int hh = v >> 6, cq = v & 63;
        *(uint4*)&P_lds[hh * 520 + cq * 8] =
            *(const uint4*)&Pbf[((size_t)hh * Nres + i) * 512 + cq * 8];
    }
    for (int l = tid; l < 4 * 520; l += 256) P_lds[12 * 520 + l] = 0;

    *(uint4*)&Bs[0][srow * 40 + sko]        = rb0;
    *(uint4*)&Bs[0][(64 + srow) * 40 + sko] = rb1;
    __syncthreads();

    const int lrow = ln & 15, lq = ln >> 4;
    const int wn = wv * 32;
    f32x4 zero = {0.f, 0.f, 0.f, 0.f};
    f32x4 acc0 = zero, acc1 = zero;
    int buf = 0;
    for (int k0 = 0; k0 < Nres; k0 += 32) {
        const bool nxt = (k0 + 32 < Nres);
        if (nxt) {
            rb0 = *(const uint4*)&Bp[b0off + k0 + 32];
            rb1 = *(const uint4*)&Bp[b1off + k0 + 32];
        }
        bf16x8 a  = *reinterpret_cast<const bf16x8*>(&P_lds[lrow * 520 + k0 + lq * 8]);
        bf16x8 b0 = *reinterpret_cast<const bf16x8*>(&Bs[buf][(wn + lrow) * 40 + lq * 8]);
        bf16x8 b1 = *reinterpret_cast<const bf16x8*>(&Bs[buf][(wn + 16 + lrow) * 40 + lq * 8]);
        acc0 = __builtin_amdgcn_mfma_f32_16x16x32_bf16(a, b0, acc0, 0, 0, 0);
        acc1 = __builtin_amdgcn_mfma_f32_16x16x32_bf16(a, b1, acc1, 0, 0, 0);
        if (nxt) {
            *(uint4*)&Bs[buf ^ 1][srow * 40 + sko]        = rb0;
            *(uint4*)&Bs[buf ^ 1][(64 + srow) * 40 + sko] = rb1;
            __syncthreads();
            buf ^= 1;
        }
    }
    u16* crow = cat_bf + (size_t)i * CATD + 576;
#pragma unroll
    for (int r = 0; r < 4; r++) {
        int row = lq * 4 + r;
        if (row < NH) {
            crow[row * Cz + wn + lrow]      = f2bf(acc0[r]);
            crow[row * Cz + wn + 16 + lrow] = f2bf(acc1[r]);
        }
    }
}

// ---------------- fused: split-K reduce (+bias) + residual add + LayerNorm ----------------
__global__ void k_reduce_ln(const float* __restrict__ P, const float* __restrict__ bias,
                            float* __restrict__ s, u16* __restrict__ s_bf,
                            const float* __restrict__ g, const float* __restrict__ b,
                            int nsplit) {
    __shared__ float red[512];
    int i = blockIdx.x, tid = threadIdx.x;
    float v = s[(size_t)i * Cs + tid];
    if (bias) v += bias[tid];
    for (int sp = 0; sp < nsplit; sp++) v += P[(size_t)sp * Nres * Cs + (size_t)i * Cs + tid];
    red[tid] = v;
    if (tid < 128) red[384 + tid] = 0.f;
    __syncthreads();
    for (int st = 256; st > 0; st >>= 1) { if (tid < st) red[tid] += red[tid + st]; __syncthreads(); }
    float mean = red[0] / Cs;
    __syncthreads();
    float d = v - mean;
    red[tid] = d * d;
    if (tid < 128) red[384 + tid] = 0.f;
    __syncthreads();
    for (int st = 256; st > 0; st >>= 1) { if (tid < st) red[tid] += red[tid + st]; __syncthreads(); }
    float var = red[0] / Cs;
    float o = d * rsqrtf(var + 1e-5f) * g[tid] + b[tid];
    s[(size_t)i * Cs + tid] = o;
    s_bf[(size_t)i * Cs + tid] = f2bf(o);
}

// ---------------- fused: reduce + residual + LN + backbone update (+ optional final pack) ----------------
__global__ void k_reduce_ln_bb(const float* __restrict__ P, float* __restrict__ s,
                               u16* __restrict__ s_bf,
                               const float* __restrict__ g, const float* __restrict__ b,
                               int nsplit,
                               const float* __restrict__ w_bb, const float* __restrict__ b_bb,
                               float* __restrict__ R, float* __restrict__ t,
                               float* __restrict__ outbuf) {
    __shared__ float red[512];
    __shared__ float uw[36];
    int i = blockIdx.x, tid = threadIdx.x;
    float v = s[(size_t)i * Cs + tid];
    for (int sp = 0; sp < nsplit; sp++) v += P[(size_t)sp * Nres * Cs + (size_t)i * Cs + tid];
    red[tid] = v;
    if (tid < 128) red[384 + tid] = 0.f;
    __syncthreads();
    for (int st = 256; st > 0; st >>= 1) { if (tid < st) red[tid] += red[tid + st]; __syncthreads(); }
    float mean = red[0] / Cs;
    __syncthreads();
    float d = v - mean;
    red[tid] = d * d;
    if (tid < 128) red[384 + tid] = 0.f;
    __syncthreads();
    for (int st = 256; st > 0; st >>= 1) { if (tid < st) red[tid] += red[tid + st]; __syncthreads(); }
    float var = red[0] / Cs;
    float o = d * rsqrtf(var + 1e-5f) * g[tid] + b[tid];
    s[(size_t)i * Cs + tid] = o;
    s_bf[(size_t)i * Cs + tid] = f2bf(o);
    if (outbuf) outbuf[(size_t)i * (Cs + 3) + tid] = o;

    float u[6];
#pragma unroll
    for (int dd = 0; dd < 6; dd++) u[dd] = o * w_bb[tid * 6 + dd];
#pragma unroll
    for (int off = 32; off > 0; off >>= 1)
#pragma unroll
        for (int dd = 0; dd < 6; dd++) u[dd] += __shfl_xor(u[dd], off);
    int wv = tid >> 6, lane = tid & 63;
    if (lane == 0) {
#pragma unroll
        for (int dd = 0; dd < 6; dd++) uw[wv * 6 + dd] = u[dd];
    }
    __syncthreads();
    if (tid == 0) {
        float uu[6];
#pragma unroll
        for (int dd = 0; dd < 6; dd++) {
            float a = b_bb[dd];
            for (int w = 0; w < 6; w++) a += uw[w * 6 + dd];
            uu[dd] = a;
        }
        float qb = uu[0], qc = uu[1], qd = uu[2];
        float inv = rsqrtf(1.f + qb*qb + qc*qc + qd*qd);
        float w = inv, x = qb * inv, y = qc * inv, zq = qd * inv;
        float Ru[9] = {
            1.f - 2.f*(y*y + zq*zq), 2.f*(x*y - w*zq),       2.f*(x*zq + w*y),
            2.f*(x*y + w*zq),        1.f - 2.f*(x*x + zq*zq), 2.f*(y*zq - w*x),
            2.f*(x*zq - w*y),        2.f*(y*zq + w*x),        1.f - 2.f*(x*x + y*y)
        };
        float Ro[9];
#pragma unroll
        for (int e = 0; e < 9; e++) Ro[e] = R[i * 9 + e];
        float tu0 = uu[3], tu1 = uu[4], tu2 = uu[5];
        float t0 = t[i*3+0] + Ro[0]*tu0 + Ro[1]*tu1 + Ro[2]*tu2;
        float t1 = t[i*3+1] + Ro[3]*tu0 + Ro[4]*tu1 + Ro[5]*tu2;
        float t2 = t[i*3+2] + Ro[6]*tu0 + Ro[7]*tu1 + Ro[8]*tu2;
        t[i*3+0] = t0; t[i*3+1] = t1; t[i*3+2] = t2;
        if (outbuf) {
            outbuf[(size_t)i * (Cs + 3) + Cs + 0] = t0;
            outbuf[(size_t)i * (Cs + 3) + Cs + 1] = t1;
            outbuf[(size_t)i * (Cs + 3) + Cs + 2] = t2;
        }
#pragma unroll
        for (int r = 0; r < 3; r++)
#pragma unroll
            for (int c = 0; c < 3; c++)
                R[i*9 + r*3 + c] = Ro[r*3+0]*Ru[0*3+c] + Ro[r*3+1]*Ru[1*3+c] + Ro[r*3+2]*Ru[2*3+c];
    }
}

// ---------------- launch ----------------
extern "C" void kernel_launch(void* const* d_in, const int* in_sizes, int n_in,
                              void* d_out, int out_size, void* d_ws, size_t ws_size,
                              hipStream_t stream) {
    const float* s_in    = (const float*)d_in[0];
    const float* z       = (const float*)d_in[1];
    const float* w_q     = (const float*)d_in[2];
    const float* w_kv    = (const float*)d_in[3];
    const float* w_qpts  = (const float*)d_in[4];
    const float* w_kvpts = (const float*)d_in[5];
    const float* w_b     = (const float*)d_in[6];
    const float* hw      = (const float*)d_in[7];
    const float* w_out   = (const float*)d_in[8];
    const float* b_out   = (const float*)d_in[9];
    const float* ln1_g   = (const float*)d_in[10];
    const float* ln1_b   = (const float*)d_in[11];
    const float* w_t1    = (const float*)d_in[12];
    const float* w_t2    = (const float*)d_in[13];
    const float* w_t3    = (const float*)d_in[14];
    const float* ln2_g   = (const float*)d_in[15];
    const float* ln2_b   = (const float*)d_in[16];
    const float* w_bb    = (const float*)d_in[17];
    const float* b_bb    = (const float*)d_in[18];
    float* out = (float*)d_out;

    float* ws = (float*)d_ws;
    size_t off = 0;
    float* s_cur = ws + off; off += (size_t)Nres * Cs;
    float* projT = ws + off; off += (size_t)2 * Nres * PROJD;   // 2 split-K slabs
    float* Wcat  = ws + off; off += (size_t)Cs * PROJD;
    float* Rbuf  = ws + off; off += (size_t)Nres * 9;
    float* tbuf  = ws + off; off += (size_t)Nres * 3;
    float* Pslab = ws + off; off += (size_t)12 * Nres * Cs;
    // bf16 buffers (carved in float units, halved counts)
    u16* b_hij_bf = (u16*)(ws + off); off += (size_t)NH * Nres * Nres / 2;
    u16* s_bf   = (u16*)(ws + off); off += (size_t)Nres * Cs / 2;
    u16* cat_bf = (u16*)(ws + off); off += (size_t)Nres * CATD / 2;
    u16* WcatT  = (u16*)(ws + off); off += (size_t)Cs * PROJD / 2;
    u16* w_outT = (u16*)(ws + off); off += (size_t)CATD * Cs / 2;
    u16* w_t1T  = (u16*)(ws + off); off += (size_t)Cs * Cs / 2;
    u16* w_t2T  = (u16*)(ws + off); off += (size_t)Cs * Cs / 2;
    u16* w_t3T  = (u16*)(ws + off); off += (size_t)Cs * Cs / 2;
    u16* Pbf    = (u16*)(ws + off); off += (size_t)NH * Nres * Nres / 2;
    u16* vhTbf  = (u16*)(ws + off); off += (size_t)NH * 48 * Nres / 2;
    u16* Aaug   = (u16*)(ws + off); off += (size_t)NH * Nres * 32 / 2;
    u16* Baug   = (u16*)(ws + off); off += (size_t)NH * Nres * 32 / 2;
    u16* zTbf   = (u16*)(ws + off); off += (size_t)Nres * Cz * Nres / 2;

    const size_t MNs = (size_t)Nres * Cs;

    k_init<<<gdiv(Nres*Cs, 256), 256, 0, stream>>>(s_in, s_cur, s_bf, Rbuf, tbuf);
    k_concatW<<<gdiv(Cs*PROJD, 256), 256, 0, stream>>>(w_q, w_kv, w_qpts, w_kvpts, Wcat);
    k_transposeW<<<dim3(PROJD/32, Cs/32), 256, 0, stream>>>(Wcat, WcatT, Cs, PROJD);
    k_transposeW<<<dim3(Cs/32, CATD/32), 256, 0, stream>>>(w_out, w_outT, CATD, Cs);
    k_transposeW<<<dim3(Cs/32, Cs/32), 256, 0, stream>>>(w_t1, w_t1T, Cs, Cs);
    k_transposeW<<<dim3(Cs/32, Cs/32), 256, 0, stream>>>(w_t2, w_t2T, Cs, Cs);
    k_transposeW<<<dim3(Cs/32, Cs/32), 256, 0, stream>>>(w_t3, w_t3T, Cs, Cs);
    k_bproj<<<Nres*Nres/16, 256, 0, stream>>>(z, w_b, b_hij_bf);
    k_zT<<<dim3(Nres, Nres/32, Cz/32), 256, 0, stream>>>(z, zTbf);

    for (int it = 0; it < NBLK; it++) {
        // projT slabs = (s @ Wcat)^T, split-K=2 (576 blocks, 6 steps)
        k_gemm_proj<<<dim3(PROJD/64, Nres/32, 2), 256, 0, stream>>>(s_bf, WcatT, projT, Nres, Cs, PROJD);
        // point transforms + augmented QK factors + V staging (sums 2 proj slabs)
        k_prep<<<gdiv(NH*Nres, 256), 256, 0, stream>>>(projT, Rbuf, tbuf, hw, Aaug, Baug, vhTbf);
        // fused attention (384 blocks)
        k_attn<<<dim3(Nres/16, NH), 256, 0, stream>>>(Aaug, Baug, b_hij_bf, vhTbf, Rbuf, tbuf, Pbf, cat_bf);
        // o_pair (512 blocks, HBM-bound on zT)
        k_opair<<<Nres, 256, 0, stream>>>(Pbf, zTbf, cat_bf);
        // w_out GEMM: split-K=11 (1056 blocks, 6 steps) -> slabs 0..10, fused LN1
        k_gemm_sk<<<dim3(Cs/64, Nres/32, 11), 256, 0, stream>>>(cat_bf, nullptr, w_outT, Pslab, CATD, 192);
        k_reduce_ln<<<Nres, Cs, 0, stream>>>(Pslab, b_out, s_cur, s_bf, ln1_g, ln1_b, 11);
        // transitions: split-K=4 (384 blocks, 3 steps), relu+4-slab reduce fused into A-staging
        k_gemm_sk<<<dim3(Cs/64, Nres/32, 4), 256, 0, stream>>>(s_bf, nullptr, w_t1T, Pslab, Cs, 96);
        k_gemm_sk<<<dim3(Cs/64, Nres/32, 4), 256, 0, stream>>>(nullptr, Pslab, w_t2T, Pslab + 4*MNs, Cs, 96);
        k_gemm_sk<<<dim3(Cs/64, Nres/32, 4), 256, 0, stream>>>(nullptr, Pslab + 4*MNs, w_t3T, Pslab + 8*MNs, Cs, 96);
        // fused: residual + LN2 + backbone (+ final pack on last iter), 4 slabs
        k_reduce_ln_bb<<<Nres, Cs, 0, stream>>>(Pslab + 8*MNs, s_cur, s_bf, ln2_g, ln2_b, 4,
                                                w_bb, b_bb, Rbuf, tbuf,
                                                (it == NBLK - 1) ? out : nullptr);
    }
}

// Round 8
// 841.200 us; speedup vs baseline: 1.0336x; 1.0336x over previous
//
#include <hip/hip_runtime.h>
#include <hip/hip_bf16.h>

// ---------------- problem constants ----------------
constexpr int Nres = 512;
constexpr int Cs   = 384;
constexpr int Cz   = 128;
constexpr int NH   = 12;
constexpr int HC   = 16;
constexpr int NPQ  = 4;
constexpr int NPV  = 8;
constexpr int NBLK = 8;
constexpr int PROJD = NH*HC + NH*2*HC + NH*NPQ*3 + NH*(NPQ+NPV)*3; // 1152
constexpr int CATD = NH*HC + NH*NPV*3 + NH*NPV + NH*Cz;            // 2112
constexpr float W_L  = 0.57735026918962576f;  // sqrt(1/3)
constexpr float W_C2 = 0.11785113019775793f;  // sqrt(2/(9*PQ)) / 2

using u16 = unsigned short;
typedef __bf16 bf16x8 __attribute__((ext_vector_type(8)));
typedef float  f32x4  __attribute__((ext_vector_type(4)));

static inline int gdiv(int n, int b) { return (n + b - 1) / b; }

static __device__ __forceinline__ u16 f2bf(float x) {
    __hip_bfloat16 h = __float2bfloat16(x);
    return *reinterpret_cast<u16*>(&h);
}
static __device__ __forceinline__ float bf2f(u16 x) {
    return __bfloat162float(*reinterpret_cast<__hip_bfloat16*>(&x));
}

// ---------------- init ----------------
__global__ void k_init(const float* __restrict__ s_in, float* __restrict__ s_cur,
                       u16* __restrict__ s_bf,
                       float* __restrict__ R, float* __restrict__ t) {
    int idx = blockIdx.x * blockDim.x + threadIdx.x;
    if (idx < Nres * Cs) { float v = s_in[idx]; s_cur[idx] = v; s_bf[idx] = f2bf(v); }
    if (idx < Nres * 9) {
        int e = idx % 9;
        R[idx] = (e == 0 || e == 4 || e == 8) ? 1.f : 0.f;
    }
    if (idx < Nres * 3) t[idx] = 0.f;
}

// concat projection weights into Wcat[384][1152] (fp32 staging for transpose)
__global__ void k_concatW(const float* __restrict__ w_q, const float* __restrict__ w_kv,
                          const float* __restrict__ w_qpts, const float* __restrict__ w_kvpts,
                          float* __restrict__ Wcat) {
    int idx = blockIdx.x * blockDim.x + threadIdx.x;
    if (idx >= Cs * PROJD) return;
    int k = idx / PROJD, n = idx - k * PROJD;
    float v;
    if      (n < 192) v = w_q[k * 192 + n];
    else if (n < 576) v = w_kv[k * 384 + (n - 192)];
    else if (n < 720) v = w_qpts[k * 144 + (n - 576)];
    else              v = w_kvpts[k * 432 + (n - 720)];
    Wcat[idx] = v;
}

// transpose + bf16 convert: out[n][k] = in[k][n]; K,N multiples of 32
__global__ void k_transposeW(const float* __restrict__ in, u16* __restrict__ out,
                             int K, int N) {
    __shared__ float tile[32][33];
    int n0 = blockIdx.x * 32, k0 = blockIdx.y * 32;
    int tx = threadIdx.x & 31, ty = threadIdx.x >> 5;   // ty 0..7
#pragma unroll
    for (int j = 0; j < 4; j++)
        tile[ty + j * 8][tx] = in[(size_t)(k0 + ty + j * 8) * N + n0 + tx];
    __syncthreads();
#pragma unroll
    for (int j = 0; j < 4; j++)
        out[(size_t)(n0 + ty + j * 8) * K + k0 + tx] = f2bf(tile[tx][ty + j * 8]);
}

// one-time: z[i][j][c] fp32 -> zT[i][c][j] bf16
__global__ void k_zT(const float* __restrict__ z, u16* __restrict__ zT) {
    __shared__ float tile[32][33];
    int i  = blockIdx.x;
    int j0 = blockIdx.y * 32;
    int c0 = blockIdx.z * 32;
    int tx = threadIdx.x & 31, ty = threadIdx.x >> 5;   // ty 0..7
    const float* src = z + (size_t)i * Nres * Cz;
#pragma unroll
    for (int l = 0; l < 4; l++)
        tile[ty + l * 8][tx] = src[(size_t)(j0 + ty + l * 8) * Cz + c0 + tx];
    __syncthreads();
    u16* dst = zT + (size_t)i * Cz * Nres;
#pragma unroll
    for (int l = 0; l < 4; l++)
        dst[(size_t)(c0 + ty + l * 8) * Nres + j0 + tx] = f2bf(tile[tx][ty + l * 8]);
}

// ---------------- split-K MFMA GEMM, 64x64 tile, double-buffered (w_out) ----------------
__global__ void __launch_bounds__(256)
k_gemm_mfma(const u16* __restrict__ A, const u16* __restrict__ Bt,
            float* __restrict__ P, int M, int K, int N, int Kc) {
    __shared__ u16 As[2][64 * 40];
    __shared__ u16 Bs[2][64 * 40];
    const int tid = threadIdx.x;
    const int m0 = blockIdx.y * 64;
    const int n0 = blockIdx.x * 64;
    const int kbeg = blockIdx.z * Kc;
    const int kend = kbeg + Kc;
    const int wv = tid >> 6, lane = tid & 63;
    const int wm = (wv >> 1) * 32, wn = (wv & 1) * 32;
    const int lrow = lane & 15, lq = lane >> 4;

    f32x4 zero = {0.f, 0.f, 0.f, 0.f};
    f32x4 acc00 = zero, acc01 = zero, acc10 = zero, acc11 = zero;

    const int srow = tid >> 2;
    const int sko  = (tid & 3) * 8;
    const size_t aoff = (size_t)(m0 + srow) * K + sko;
    const size_t boff = (size_t)(n0 + srow) * K + sko;

    uint4 ra = *(const uint4*)&A[aoff + kbeg];
    uint4 rb = *(const uint4*)&Bt[boff + kbeg];
    *(uint4*)&As[0][srow * 40 + sko] = ra;
    *(uint4*)&Bs[0][srow * 40 + sko] = rb;
    __syncthreads();

    int buf = 0;
    for (int k0 = kbeg; k0 < kend; k0 += 32) {
        const bool nxt = (k0 + 32 < kend);
        if (nxt) {
            ra = *(const uint4*)&A[aoff + k0 + 32];
            rb = *(const uint4*)&Bt[boff + k0 + 32];
        }
        bf16x8 a0 = *reinterpret_cast<const bf16x8*>(&As[buf][(wm + lrow) * 40 + lq * 8]);
        bf16x8 a1 = *reinterpret_cast<const bf16x8*>(&As[buf][(wm + 16 + lrow) * 40 + lq * 8]);
        bf16x8 b0 = *reinterpret_cast<const bf16x8*>(&Bs[buf][(wn + lrow) * 40 + lq * 8]);
        bf16x8 b1 = *reinterpret_cast<const bf16x8*>(&Bs[buf][(wn + 16 + lrow) * 40 + lq * 8]);
        acc00 = __builtin_amdgcn_mfma_f32_16x16x32_bf16(a0, b0, acc00, 0, 0, 0);
        acc01 = __builtin_amdgcn_mfma_f32_16x16x32_bf16(a0, b1, acc01, 0, 0, 0);
        acc10 = __builtin_amdgcn_mfma_f32_16x16x32_bf16(a1, b0, acc10, 0, 0, 0);
        acc11 = __builtin_amdgcn_mfma_f32_16x16x32_bf16(a1, b1, acc11, 0, 0, 0);
        if (nxt) {
            *(uint4*)&As[buf ^ 1][srow * 40 + sko] = ra;
            *(uint4*)&Bs[buf ^ 1][srow * 40 + sko] = rb;
            __syncthreads();
            buf ^= 1;
        }
    }
    float* Pp = P + (size_t)blockIdx.z * M * N;
    const int rbase = m0 + wm + lq * 4;
    const int cbase = n0 + wn + lrow;
#pragma unroll
    for (int r = 0; r < 4; r++) {
        Pp[(size_t)(rbase + r) * N + cbase]           = acc00[r];
        Pp[(size_t)(rbase + r) * N + cbase + 16]      = acc01[r];
        Pp[(size_t)(rbase + 16 + r) * N + cbase]      = acc10[r];
        Pp[(size_t)(rbase + 16 + r) * N + cbase + 16] = acc11[r];
    }
}

// ---------------- proj GEMM: full-K, 32x64 tile, dbuf, TRANSPOSED fp32 out ----------------
__global__ void __launch_bounds__(256)
k_gemm_proj(const u16* __restrict__ A, const u16* __restrict__ Bt,
            float* __restrict__ outT, int M, int K, int N) {
    __shared__ u16 As[2][32 * 40];
    __shared__ u16 Bs[2][64 * 40];
    const int tid = threadIdx.x;
    const int m0 = blockIdx.y * 32;
    const int n0 = blockIdx.x * 64;
    const int wv = tid >> 6, lane = tid & 63;
    const int wm = (wv >> 1) * 16, wn = (wv & 1) * 32;
    const int lrow = lane & 15, lq = lane >> 4;
    f32x4 zero = {0.f, 0.f, 0.f, 0.f};
    f32x4 acc0 = zero, acc1 = zero;
    const int srow = tid >> 2, sko = (tid & 3) * 8;
    const size_t aoff = (size_t)(m0 + srow) * K + sko;   // valid for tid<128
    const size_t boff = (size_t)(n0 + srow) * K + sko;

    uint4 ra, rb;
    if (tid < 128) ra = *(const uint4*)&A[aoff];
    rb = *(const uint4*)&Bt[boff];
    if (tid < 128) *(uint4*)&As[0][srow * 40 + sko] = ra;
    *(uint4*)&Bs[0][srow * 40 + sko] = rb;
    __syncthreads();

    int buf = 0;
    for (int k0 = 0; k0 < K; k0 += 32) {
        const bool nxt = (k0 + 32 < K);
        if (nxt) {
            if (tid < 128) ra = *(const uint4*)&A[aoff + k0 + 32];
            rb = *(const uint4*)&Bt[boff + k0 + 32];
        }
        bf16x8 a  = *reinterpret_cast<const bf16x8*>(&As[buf][(wm + lrow) * 40 + lq * 8]);
        bf16x8 b0 = *reinterpret_cast<const bf16x8*>(&Bs[buf][(wn + lrow) * 40 + lq * 8]);
        bf16x8 b1 = *reinterpret_cast<const bf16x8*>(&Bs[buf][(wn + 16 + lrow) * 40 + lq * 8]);
        acc0 = __builtin_amdgcn_mfma_f32_16x16x32_bf16(a, b0, acc0, 0, 0, 0);
        acc1 = __builtin_amdgcn_mfma_f32_16x16x32_bf16(a, b1, acc1, 0, 0, 0);
        if (nxt) {
            if (tid < 128) *(uint4*)&As[buf ^ 1][srow * 40 + sko] = ra;
            *(uint4*)&Bs[buf ^ 1][srow * 40 + sko] = rb;
            __syncthreads();
            buf ^= 1;
        }
    }
    const int rbase = m0 + wm + lq * 4;
    const int cbase = n0 + wn + lrow;
    *reinterpret_cast<f32x4*>(&outT[(size_t)cbase * M + rbase])        = acc0;
    *reinterpret_cast<f32x4*>(&outT[(size_t)(cbase + 16) * M + rbase]) = acc1;
}

// ---------------- transition GEMM: split-K=2, fused A-side (reduce+relu) staging ----------------
__global__ void __launch_bounds__(256)
k_gemm_tr(const u16* __restrict__ Abf, const float* __restrict__ As0,
          const float* __restrict__ As1, const u16* __restrict__ Bt,
          float* __restrict__ Pout, int amode) {
    __shared__ u16 Asm[2][32 * 40];
    __shared__ u16 Bsm[2][64 * 40];
    const int tid = threadIdx.x;
    const int m0 = blockIdx.y * 32;
    const int n0 = blockIdx.x * 64;
    const int kbeg = blockIdx.z * 192;
    const int kend = kbeg + 192;
    const int wv = tid >> 6, lane = tid & 63;
    const int wm = (wv >> 1) * 16, wn = (wv & 1) * 32;
    const int lrow = lane & 15, lq = lane >> 4;
    f32x4 zero = {0.f, 0.f, 0.f, 0.f};
    f32x4 acc0 = zero, acc1 = zero;
    const int srow = tid >> 2, sko = (tid & 3) * 8;
    const int rowR = tid >> 3, c4 = (tid & 7) * 4;
    const size_t aoffb = (size_t)(m0 + srow) * Cs + sko;
    const size_t aoffr = (size_t)(m0 + rowR) * Cs + c4;
    const size_t boff  = (size_t)(n0 + srow) * Cs + sko;

    uint4 ra, rb;
    float4 f0, f1;
    rb = *(const uint4*)&Bt[boff + kbeg];
    if (amode == 0) { if (tid < 128) ra = *(const uint4*)&Abf[aoffb + kbeg]; }
    else { f0 = *(const float4*)&As0[aoffr + kbeg]; f1 = *(const float4*)&As1[aoffr + kbeg]; }

    if (amode == 0) { if (tid < 128) *(uint4*)&Asm[0][srow * 40 + sko] = ra; }
    else {
        uint2 wp;
        wp.x = (unsigned)f2bf(fmaxf(f0.x + f1.x, 0.f)) | ((unsigned)f2bf(fmaxf(f0.y + f1.y, 0.f)) << 16);
        wp.y = (unsigned)f2bf(fmaxf(f0.z + f1.z, 0.f)) | ((unsigned)f2bf(fmaxf(f0.w + f1.w, 0.f)) << 16);
        *(uint2*)&Asm[0][rowR * 40 + c4] = wp;
    }
    *(uint4*)&Bsm[0][srow * 40 + sko] = rb;
    __syncthreads();

    int buf = 0;
    for (int k0 = kbeg; k0 < kend; k0 += 32) {
        const bool nxt = (k0 + 32 < kend);
        if (nxt) {
            rb = *(const uint4*)&Bt[boff + k0 + 32];
            if (amode == 0) { if (tid < 128) ra = *(const uint4*)&Abf[aoffb + k0 + 32]; }
            else { f0 = *(const float4*)&As0[aoffr + k0 + 32]; f1 = *(const float4*)&As1[aoffr + k0 + 32]; }
        }
        bf16x8 a  = *reinterpret_cast<const bf16x8*>(&Asm[buf][(wm + lrow) * 40 + lq * 8]);
        bf16x8 b0 = *reinterpret_cast<const bf16x8*>(&Bsm[buf][(wn + lrow) * 40 + lq * 8]);
        bf16x8 b1 = *reinterpret_cast<const bf16x8*>(&Bsm[buf][(wn + 16 + lrow) * 40 + lq * 8]);
        acc0 = __builtin_amdgcn_mfma_f32_16x16x32_bf16(a, b0, acc0, 0, 0, 0);
        acc1 = __builtin_amdgcn_mfma_f32_16x16x32_bf16(a, b1, acc1, 0, 0, 0);
        if (nxt) {
            if (amode == 0) { if (tid < 128) *(uint4*)&Asm[buf ^ 1][srow * 40 + sko] = ra; }
            else {
                uint2 wp;
                wp.x = (unsigned)f2bf(fmaxf(f0.x + f1.x, 0.f)) | ((unsigned)f2bf(fmaxf(f0.y + f1.y, 0.f)) << 16);
                wp.y = (unsigned)f2bf(fmaxf(f0.z + f1.z, 0.f)) | ((unsigned)f2bf(fmaxf(f0.w + f1.w, 0.f)) << 16);
                *(uint2*)&Asm[buf ^ 1][rowR * 40 + c4] = wp;
            }
            *(uint4*)&Bsm[buf ^ 1][srow * 40 + sko] = rb;
            __syncthreads();
            buf ^= 1;
        }
    }
    float* Pp = Pout + (size_t)blockIdx.z * Nres * Cs;
    const int rbase = m0 + wm + lq * 4;
    const int cbase = n0 + wn + lrow;
#pragma unroll
    for (int r = 0; r < 4; r++) {
        Pp[(size_t)(rbase + r) * Cs + cbase]      = acc0[r];
        Pp[(size_t)(rbase + r) * Cs + cbase + 16] = acc1[r];
    }
}

// ---------------- b_hij (once), pre-scaled by W_L, bf16 out ----------------
__global__ void k_bproj(const float* __restrict__ z, const float* __restrict__ w_b,
                        u16* __restrict__ b_hij_bf) {
    __shared__ float zs[16][129];
    __shared__ float wbs[Cz * NH];
    const int tid = threadIdx.x;
    const int base = blockIdx.x * 16;
#pragma unroll
    for (int l = 0; l < 6; l++) {
        int idx = tid + l * 256;
        if (idx < Cz * NH) wbs[idx] = w_b[idx];
    }
#pragma unroll
    for (int l = 0; l < 8; l++) {
        int idx = tid + l * 256;
        int r = idx >> 7, c = idx & 127;
        zs[r][c] = z[(size_t)(base + r) * Cz + c];
    }
    __syncthreads();
    if (tid < 192) {
        int h = tid >> 4, r = tid & 15;
        float acc = 0.f;
        for (int c = 0; c < Cz; c++) acc += zs[r][c] * wbs[c * NH + h];
        int row = base + r;
        int i = row >> 9, j = row & 511;
        b_hij_bf[((size_t)h * Nres + i) * Nres + j] = f2bf(acc * W_L);
    }
}

// ---------------- prep: build Aaug/Baug + vhT from TRANSPOSED projT (coalesced) ----------------
__global__ void k_prep(const float* __restrict__ projT, const float* __restrict__ R,
                       const float* __restrict__ t, const float* __restrict__ hw,
                       u16* __restrict__ Aaug, u16* __restrict__ Baug,
                       u16* __restrict__ vhT) {
    int idx = blockIdx.x * blockDim.x + threadIdx.x;
    if (idx >= NH * Nres) return;
    int h = idx / Nres, i = idx % Nres;
#define PR(col) projT[(size_t)(col) * Nres + i]
    float R_[9], t_[3];
#pragma unroll
    for (int e = 0; e < 9; e++) R_[e] = R[i * 9 + e];
#pragma unroll
    for (int e = 0; e < 3; e++) t_[e] = t[i * 3 + e];
    float gam = log1pf(__expf(hw[h]));
    float ch  = sqrtf(2.f * gam * W_C2);

    u16 arow[32], brow[32];
#pragma unroll
    for (int c = 0; c < HC; c++) {
        arow[c] = f2bf(PR(h * HC + c) * (W_L * 0.25f));
        brow[c] = f2bf(PR(192 + h * 2 * HC + c));
        vhT[((size_t)h * 48 + c) * Nres + i] = f2bf(PR(192 + h * 2 * HC + HC + c));
    }
#pragma unroll
    for (int p = 0; p < NPQ; p++) {
        int c0 = 576 + (h * NPQ + p) * 3;
        float y0 = PR(c0 + 0), y1 = PR(c0 + 1), y2 = PR(c0 + 2);
        float v0 = R_[0]*y0 + R_[1]*y1 + R_[2]*y2 + t_[0];
        float v1 = R_[3]*y0 + R_[4]*y1 + R_[5]*y2 + t_[1];
        float v2 = R_[6]*y0 + R_[7]*y1 + R_[8]*y2 + t_[2];
        float s = W_L * ch;
        arow[16 + p*3 + 0] = f2bf(v0 * s);
        arow[16 + p*3 + 1] = f2bf(v1 * s);
        arow[16 + p*3 + 2] = f2bf(v2 * s);
    }
    float sk = 0.f;
#pragma unroll
    for (int p = 0; p < NPQ + NPV; p++) {
        int c0 = 720 + (h * (NPQ+NPV) + p) * 3;
        float y0 = PR(c0 + 0), y1 = PR(c0 + 1), y2 = PR(c0 + 2);
        float v0 = R_[0]*y0 + R_[1]*y1 + R_[2]*y2 + t_[0];
        float v1 = R_[3]*y0 + R_[4]*y1 + R_[5]*y2 + t_[1];
        float v2 = R_[6]*y0 + R_[7]*y1 + R_[8]*y2 + t_[2];
        if (p < NPQ) {
            brow[16 + p*3 + 0] = f2bf(v0 * ch);
            brow[16 + p*3 + 1] = f2bf(v1 * ch);
            brow[16 + p*3 + 2] = f2bf(v2 * ch);
            sk += v0*v0 + v1*v1 + v2*v2;
        } else {
            int cc = 16 + (p - NPQ) * 3;
            vhT[((size_t)h * 48 + cc + 0) * Nres + i] = f2bf(v0);
            vhT[((size_t)h * 48 + cc + 1) * Nres + i] = f2bf(v1);
            vhT[((size_t)h * 48 + cc + 2) * Nres + i] = f2bf(v2);
        }
    }
#undef PR
    float x = -W_L * gam * W_C2 * sk;
    u16 hi = f2bf(x);
    float lo = x - bf2f(hi);
    arow[28] = f2bf(1.0f); arow[29] = f2bf(1.0f); arow[30] = 0; arow[31] = 0;
    brow[28] = hi;         brow[29] = f2bf(lo);   brow[30] = 0; brow[31] = 0;

    uint4* ad = (uint4*)&Aaug[((size_t)h * Nres + i) * 32];
    uint4* bd = (uint4*)&Baug[((size_t)h * Nres + i) * 32];
    const uint4* as = (const uint4*)arow;
    const uint4* bs = (const uint4*)brow;
#pragma unroll
    for (int e = 0; e < 4; e++) { ad[e] = as[e]; bd[e] = bs[e]; }
}

// ---------------- fused attention v2: 16-row tiles, direct-global fragments ----------------
// grid (Nres/16, NH), 256 threads. Wave w: QK j-quarter w, ov K-quarter w.
__global__ void __launch_bounds__(256)
k_attn(const u16* __restrict__ Aaug, const u16* __restrict__ Baug,
       const u16* __restrict__ b_hij_bf, const u16* __restrict__ vhT,
       const float* __restrict__ R, const float* __restrict__ t,
       u16* __restrict__ Pbf, u16* __restrict__ cat_bf) {
    __shared__ u16 P_lds[16 * 520];       // b_hij staging, then P
    __shared__ float Ctp[4][16 * 49];     // ov partials per wave
    __shared__ float sred[4][32];         // softmax cross-wave

    const int i0 = blockIdx.x * 16;
    const int h  = blockIdx.y;
    const int tid = threadIdx.x;
    const int w = tid >> 6, lane = tid & 63;
    const int lrow = lane & 15, lq = lane >> 4;
    const int jbase = w * 128;

    const u16* bhp = b_hij_bf + ((size_t)h * Nres + i0) * Nres;
    uint4 bhreg[4];
#pragma unroll
    for (int l = 0; l < 4; l++) {
        int v = tid + l * 256;
        int rr = v >> 6, cq = v & 63;
        bhreg[l] = *(const uint4*)&bhp[(size_t)rr * Nres + cq * 8];
    }

    bf16x8 afrag = *reinterpret_cast<const bf16x8*>(
        &Aaug[((size_t)h * Nres + i0 + lrow) * 32 + lq * 8]);
    f32x4 zero = {0.f, 0.f, 0.f, 0.f};
    f32x4 acc[8];
#pragma unroll
    for (int tt = 0; tt < 8; tt++) {
        bf16x8 bfr = *reinterpret_cast<const bf16x8*>(
            &Baug[((size_t)h * Nres + jbase + tt * 16 + lrow) * 32 + lq * 8]);
        acc[tt] = __builtin_amdgcn_mfma_f32_16x16x32_bf16(afrag, bfr, zero, 0, 0, 0);
    }

#pragma unroll
    for (int l = 0; l < 4; l++) {
        int v = tid + l * 256;
        int rr = v >> 6, cq = v & 63;
        *(uint4*)&P_lds[rr * 520 + cq * 8] = bhreg[l];
    }
    __syncthreads();
#pragma unroll
    for (int tt = 0; tt < 8; tt++)
#pragma unroll
        for (int r = 0; r < 4; r++)
            acc[tt][r] += bf2f(P_lds[(lq * 4 + r) * 520 + jbase + tt * 16 + lrow]);

    float pmx[4] = {-1e30f, -1e30f, -1e30f, -1e30f};
#pragma unroll
    for (int tt = 0; tt < 8; tt++)
#pragma unroll
        for (int r = 0; r < 4; r++) pmx[r] = fmaxf(pmx[r], acc[tt][r]);
#pragma unroll
    for (int off = 8; off > 0; off >>= 1)
#pragma unroll
        for (int r = 0; r < 4; r++) pmx[r] = fmaxf(pmx[r], __shfl_xor(pmx[r], off));
    if (lrow == 0) {
#pragma unroll
        for (int r = 0; r < 4; r++) sred[w][lq * 4 + r] = pmx[r];
    }
    __syncthreads();
    float mx[4];
#pragma unroll
    for (int r = 0; r < 4; r++) {
        int row = lq * 4 + r;
        mx[r] = fmaxf(fmaxf(sred[0][row], sred[1][row]), fmaxf(sred[2][row], sred[3][row]));
    }
    float psm[4] = {0.f, 0.f, 0.f, 0.f};
#pragma unroll
    for (int tt = 0; tt < 8; tt++)
#pragma unroll
        for (int r = 0; r < 4; r++) { acc[tt][r] = __expf(acc[tt][r] - mx[r]); psm[r] += acc[tt][r]; }
#pragma unroll
    for (int off = 8; off > 0; off >>= 1)
#pragma unroll
        for (int r = 0; r < 4; r++) psm[r] += __shfl_xor(psm[r], off);
    if (lrow == 0) {
#pragma unroll
        for (int r = 0; r < 4; r++) sred[w][16 + lq * 4 + r] = psm[r];
    }
    __syncthreads();
    float inv[4];
#pragma unroll
    for (int r = 0; r < 4; r++) {
        int row = 16 + lq * 4 + r;
        inv[r] = 1.f / (sred[0][row] + sred[1][row] + sred[2][row] + sred[3][row]);
    }

#pragma unroll
    for (int tt = 0; tt < 8; tt++)
#pragma unroll
        for (int r = 0; r < 4; r++)
            P_lds[(lq * 4 + r) * 520 + jbase + tt * 16 + lrow] = f2bf(acc[tt][r] * inv[r]);
    __syncthreads();

#pragma unroll
    for (int l = 0; l < 4; l++) {
        int v = tid + l * 256;
        int rr = v >> 6, cq = v & 63;
        *(uint4*)&Pbf[((size_t)h * Nres + i0 + rr) * 512 + cq * 8] =
            *(const uint4*)&P_lds[rr * 520 + cq * 8];
    }

    const u16* Bvp = vhT + (size_t)h * 48 * Nres;
    f32x4 o0 = zero, o1 = zero, o2 = zero;
#pragma unroll
    for (int s = 0; s < 4; s++) {
        int k0 = w * 128 + s * 32;
        bf16x8 a  = *reinterpret_cast<const bf16x8*>(&P_lds[lrow * 520 + k0 + lq * 8]);
        bf16x8 b0 = *reinterpret_cast<const bf16x8*>(&Bvp[(size_t)(lrow) * Nres + k0 + lq * 8]);
        bf16x8 b1 = *reinterpret_cast<const bf16x8*>(&Bvp[(size_t)(16 + lrow) * Nres + k0 + lq * 8]);
        bf16x8 b2 = *reinterpret_cast<const bf16x8*>(&Bvp[(size_t)(32 + lrow) * Nres + k0 + lq * 8]);
        o0 = __builtin_amdgcn_mfma_f32_16x16x32_bf16(a, b0, o0, 0, 0, 0);
        o1 = __builtin_amdgcn_mfma_f32_16x16x32_bf16(a, b1, o1, 0, 0, 0);
        o2 = __builtin_amdgcn_mfma_f32_16x16x32_bf16(a, b2, o2, 0, 0, 0);
    }
#pragma unroll
    for (int r = 0; r < 4; r++) {
        int row = lq * 4 + r;
        Ctp[w][row * 49 + lrow]      = o0[r];
        Ctp[w][row * 49 + 16 + lrow] = o1[r];
        Ctp[w][row * 49 + 32 + lrow] = o2[r];
    }
    __syncthreads();

    {
        int r = tid >> 4, c = tid & 15;
        float v = Ctp[0][r * 49 + c] + Ctp[1][r * 49 + c] + Ctp[2][r * 49 + c] + Ctp[3][r * 49 + c];
        cat_bf[(size_t)(i0 + r) * CATD + h * HC + c] = f2bf(v);
    }
    if (tid < 128) {
        int r = tid >> 3, p = tid & 7;
        int i = i0 + r;
        float g0 = 0.f, g1 = 0.f, g2 = 0.f;
#pragma unroll
        for (int ww = 0; ww < 4; ww++) {
            g0 += Ctp[ww][r * 49 + 16 + p * 3 + 0];
            g1 += Ctp[ww][r * 49 + 16 + p * 3 + 1];
            g2 += Ctp[ww][r * 49 + 16 + p * 3 + 2];
        }
        float d0 = g0 - t[i * 3 + 0], d1 = g1 - t[i * 3 + 1], d2v = g2 - t[i * 3 + 2];
        const float* Rn = R + i * 9;
        float l0 = Rn[0] * d0 + Rn[3] * d1 + Rn[6] * d2v;
        float l1 = Rn[1] * d0 + Rn[4] * d1 + Rn[7] * d2v;
        float l2 = Rn[2] * d0 + Rn[5] * d1 + Rn[8] * d2v;
        int hp = h * NPV + p;
        u16* crow = cat_bf + (size_t)i * CATD;
        crow[192 + hp * 3 + 0] = f2bf(l0);
        crow[192 + hp * 3 + 1] = f2bf(l1);
        crow[192 + hp * 3 + 2] = f2bf(l2);
        crow[480 + hp] = f2bf(sqrtf(l0 * l0 + l1 * l1 + l2 * l2 + 1e-8f));
    }
}

// ---------------- o_pair MFMA (reads Pbf), z double-buffered ----------------
__global__ void __launch_bounds__(256)
k_opair(const u16* __restrict__ Pbf, const u16* __restrict__ zT,
        u16* __restrict__ cat_bf) {
    __shared__ u16 P_lds[16 * 520];
    __shared__ u16 Bs[2][128 * 40];
    const int i = blockIdx.x;
    const int tid = threadIdx.x;
    const int wv = tid >> 6, ln = tid & 63;
    const int srow = tid >> 2, sko = (tid & 3) * 8;
    const u16* Bp = zT + (size_t)i * Cz * Nres;
    const size_t b0off = (size_t)srow * Nres + sko;
    const size_t b1off = (size_t)(64 + srow) * Nres + sko;

    uint4 rb0 = *(const uint4*)&Bp[b0off];
    uint4 rb1 = *(const uint4*)&Bp[b1off];

#pragma unroll
    for (int l = 0; l < 3; l++) {
        int v = tid + l * 256;
        int hh = v >> 6, cq = v & 63;
        *(uint4*)&P_lds[hh * 520 + cq * 8] =
            *(const uint4*)&Pbf[((size_t)hh * Nres + i) * 512 + cq * 8];
    }
    for (int l = tid; l < 4 * 520; l += 256) P_lds[12 * 520 + l] = 0;

    *(uint4*)&Bs[0][srow * 40 + sko]        = rb0;
    *(uint4*)&Bs[0][(64 + srow) * 40 + sko] = rb1;
    __syncthreads();

    const int lrow = ln & 15, lq = ln >> 4;
    const int wn = wv * 32;
    f32x4 zero = {0.f, 0.f, 0.f, 0.f};
    f32x4 acc0 = zero, acc1 = zero;
    int buf = 0;
    for (int k0 = 0; k0 < Nres; k0 += 32) {
        const bool nxt = (k0 + 32 < Nres);
        if (nxt) {
            rb0 = *(const uint4*)&Bp[b0off + k0 + 32];
            rb1 = *(const uint4*)&Bp[b1off + k0 + 32];
        }
        bf16x8 a  = *reinterpret_cast<const bf16x8*>(&P_lds[lrow * 520 + k0 + lq * 8]);
        bf16x8 b0 = *reinterpret_cast<const bf16x8*>(&Bs[buf][(wn + lrow) * 40 + lq * 8]);
        bf16x8 b1 = *reinterpret_cast<const bf16x8*>(&Bs[buf][(wn + 16 + lrow) * 40 + lq * 8]);
        acc0 = __builtin_amdgcn_mfma_f32_16x16x32_bf16(a, b0, acc0, 0, 0, 0);
        acc1 = __builtin_amdgcn_mfma_f32_16x16x32_bf16(a, b1, acc1, 0, 0, 0);
        if (nxt) {
            *(uint4*)&Bs[buf ^ 1][srow * 40 + sko]        = rb0;
            *(uint4*)&Bs[buf ^ 1][(64 + srow) * 40 + sko] = rb1;
            __syncthreads();
            buf ^= 1;
        }
    }
    u16* crow = cat_bf + (size_t)i * CATD + 576;
#pragma unroll
    for (int r = 0; r < 4; r++) {
        int row = lq * 4 + r;
        if (row < NH) {
            crow[row * Cz + wn + lrow]      = f2bf(acc0[r]);
            crow[row * Cz + wn + 16 + lrow] = f2bf(acc1[r]);
        }
    }
}

// ---------------- fused: split-K reduce (+bias) + residual + LayerNorm (wave-shuffle) ----------------
__global__ void k_reduce_ln(const float* __restrict__ P, const float* __restrict__ bias,
                            float* __restrict__ s, u16* __restrict__ s_bf,
                            const float* __restrict__ g, const float* __restrict__ b,
                            int nsplit) {
    __shared__ float w1[6], w2[6];
    int i = blockIdx.x, tid = threadIdx.x;
    int wv = tid >> 6;
    float v = s[(size_t)i * Cs + tid];
    if (bias) v += bias[tid];
    for (int sp = 0; sp < nsplit; sp++) v += P[(size_t)sp * Nres * Cs + (size_t)i * Cs + tid];
    float ws = v;
#pragma unroll
    for (int off = 32; off > 0; off >>= 1) ws += __shfl_xor(ws, off);
    if ((tid & 63) == 0) w1[wv] = ws;
    __syncthreads();
    float mean = (w1[0] + w1[1] + w1[2] + w1[3] + w1[4] + w1[5]) / Cs;
    float d = v - mean;
    float ds = d * d;
#pragma unroll
    for (int off = 32; off > 0; off >>= 1) ds += __shfl_xor(ds, off);
    if ((tid & 63) == 0) w2[wv] = ds;
    __syncthreads();
    float var = (w2[0] + w2[1] + w2[2] + w2[3] + w2[4] + w2[5]) / Cs;
    float o = d * rsqrtf(var + 1e-5f) * g[tid] + b[tid];
    s[(size_t)i * Cs + tid] = o;
    s_bf[(size_t)i * Cs + tid] = f2bf(o);
}

// ---------------- fused: reduce + residual + LN + backbone update (+ optional final pack) ----------------
__global__ void k_reduce_ln_bb(const float* __restrict__ P, float* __restrict__ s,
                               u16* __restrict__ s_bf,
                               const float* __restrict__ g, const float* __restrict__ b,
                               int nsplit,
                               const float* __restrict__ w_bb, const float* __restrict__ b_bb,
                               float* __restrict__ R, float* __restrict__ t,
                               float* __restrict__ outbuf) {
    __shared__ float w1[6], w2[6];
    __shared__ float uw[36];
    int i = blockIdx.x, tid = threadIdx.x;
    int wv = tid >> 6, lane = tid & 63;
    float v = s[(size_t)i * Cs + tid];
    for (int sp = 0; sp < nsplit; sp++) v += P[(size_t)sp * Nres * Cs + (size_t)i * Cs + tid];
    float wsum = v;
#pragma unroll
    for (int off = 32; off > 0; off >>= 1) wsum += __shfl_xor(wsum, off);
    if (lane == 0) w1[wv] = wsum;
    __syncthreads();
    float mean = (w1[0] + w1[1] + w1[2] + w1[3] + w1[4] + w1[5]) / Cs;
    float d = v - mean;
    float ds = d * d;
#pragma unroll
    for (int off = 32; off > 0; off >>= 1) ds += __shfl_xor(ds, off);
    if (lane == 0) w2[wv] = ds;
    __syncthreads();
    float var = (w2[0] + w2[1] + w2[2] + w2[3] + w2[4] + w2[5]) / Cs;
    float o = d * rsqrtf(var + 1e-5f) * g[tid] + b[tid];
    s[(size_t)i * Cs + tid] = o;
    s_bf[(size_t)i * Cs + tid] = f2bf(o);
    if (outbuf) outbuf[(size_t)i * (Cs + 3) + tid] = o;

    float u[6];
#pragma unroll
    for (int dd = 0; dd < 6; dd++) u[dd] = o * w_bb[tid * 6 + dd];
#pragma unroll
    for (int off = 32; off > 0; off >>= 1)
#pragma unroll
        for (int dd = 0; dd < 6; dd++) u[dd] += __shfl_xor(u[dd], off);
    if (lane == 0) {
#pragma unroll
        for (int dd = 0; dd < 6; dd++) uw[wv * 6 + dd] = u[dd];
    }
    __syncthreads();
    if (tid == 0) {
        float uu[6];
#pragma unroll
        for (int dd = 0; dd < 6; dd++) {
            float a = b_bb[dd];
            for (int w = 0; w < 6; w++) a += uw[w * 6 + dd];
            uu[dd] = a;
        }
        float qb = uu[0], qc = uu[1], qd = uu[2];
        float inv = rsqrtf(1.f + qb*qb + qc*qc + qd*qd);
        float w = inv, x = qb * inv, y = qc * inv, zq = qd * inv;
        float Ru[9] = {
            1.f - 2.f*(y*y + zq*zq), 2.f*(x*y - w*zq),       2.f*(x*zq + w*y),
            2.f*(x*y + w*zq),        1.f - 2.f*(x*x + zq*zq), 2.f*(y*zq - w*x),
            2.f*(x*zq - w*y),        2.f*(y*zq + w*x),        1.f - 2.f*(x*x + y*y)
        };
        float Ro[9];
#pragma unroll
        for (int e = 0; e < 9; e++) Ro[e] = R[i * 9 + e];
        float tu0 = uu[3], tu1 = uu[4], tu2 = uu[5];
        float t0 = t[i*3+0] + Ro[0]*tu0 + Ro[1]*tu1 + Ro[2]*tu2;
        float t1 = t[i*3+1] + Ro[3]*tu0 + Ro[4]*tu1 + Ro[5]*tu2;
        float t2 = t[i*3+2] + Ro[6]*tu0 + Ro[7]*tu1 + Ro[8]*tu2;
        t[i*3+0] = t0; t[i*3+1] = t1; t[i*3+2] = t2;
        if (outbuf) {
            outbuf[(size_t)i * (Cs + 3) + Cs + 0] = t0;
            outbuf[(size_t)i * (Cs + 3) + Cs + 1] = t1;
            outbuf[(size_t)i * (Cs + 3) + Cs + 2] = t2;
        }
#pragma unroll
        for (int r = 0; r < 3; r++)
#pragma unroll
            for (int c = 0; c < 3; c++)
                R[i*9 + r*3 + c] = Ro[r*3+0]*Ru[0*3+c] + Ro[r*3+1]*Ru[1*3+c] + Ro[r*3+2]*Ru[2*3+c];
    }
}

// ---------------- launch ----------------
extern "C" void kernel_launch(void* const* d_in, const int* in_sizes, int n_in,
                              void* d_out, int out_size, void* d_ws, size_t ws_size,
                              hipStream_t stream) {
    const float* s_in    = (const float*)d_in[0];
    const float* z       = (const float*)d_in[1];
    const float* w_q     = (const float*)d_in[2];
    const float* w_kv    = (const float*)d_in[3];
    const float* w_qpts  = (const float*)d_in[4];
    const float* w_kvpts = (const float*)d_in[5];
    const float* w_b     = (const float*)d_in[6];
    const float* hw      = (const float*)d_in[7];
    const float* w_out   = (const float*)d_in[8];
    const float* b_out   = (const float*)d_in[9];
    const float* ln1_g   = (const float*)d_in[10];
    const float* ln1_b   = (const float*)d_in[11];
    const float* w_t1    = (const float*)d_in[12];
    const float* w_t2    = (const float*)d_in[13];
    const float* w_t3    = (const float*)d_in[14];
    const float* ln2_g   = (const float*)d_in[15];
    const float* ln2_b   = (const float*)d_in[16];
    const float* w_bb    = (const float*)d_in[17];
    const float* b_bb    = (const float*)d_in[18];
    float* out = (float*)d_out;

    float* ws = (float*)d_ws;
    size_t off = 0;
    float* s_cur = ws + off; off += (size_t)Nres * Cs;
    float* projT = ws + off; off += (size_t)Nres * PROJD;   // [PROJD][Nres] fp32
    float* Wcat  = ws + off; off += (size_t)Cs * PROJD;
    float* Rbuf  = ws + off; off += (size_t)Nres * 9;
    float* tbuf  = ws + off; off += (size_t)Nres * 3;
    float* Pslab = ws + off; off += (size_t)11 * Nres * Cs;
    // bf16 buffers (carved in float units, halved counts)
    u16* b_hij_bf = (u16*)(ws + off); off += (size_t)NH * Nres * Nres / 2;
    u16* s_bf   = (u16*)(ws + off); off += (size_t)Nres * Cs / 2;
    u16* cat_bf = (u16*)(ws + off); off += (size_t)Nres * CATD / 2;
    u16* WcatT  = (u16*)(ws + off); off += (size_t)Cs * PROJD / 2;
    u16* w_outT = (u16*)(ws + off); off += (size_t)CATD * Cs / 2;
    u16* w_t1T  = (u16*)(ws + off); off += (size_t)Cs * Cs / 2;
    u16* w_t2T  = (u16*)(ws + off); off += (size_t)Cs * Cs / 2;
    u16* w_t3T  = (u16*)(ws + off); off += (size_t)Cs * Cs / 2;
    u16* Pbf    = (u16*)(ws + off); off += (size_t)NH * Nres * Nres / 2;
    u16* vhTbf  = (u16*)(ws + off); off += (size_t)NH * 48 * Nres / 2;
    u16* Aaug   = (u16*)(ws + off); off += (size_t)NH * Nres * 32 / 2;
    u16* Baug   = (u16*)(ws + off); off += (size_t)NH * Nres * 32 / 2;
    u16* zTbf   = (u16*)(ws + off); off += (size_t)Nres * Cz * Nres / 2;

    const int MNs = Nres * Cs;

    k_init<<<gdiv(Nres*Cs, 256), 256, 0, stream>>>(s_in, s_cur, s_bf, Rbuf, tbuf);
    k_concatW<<<gdiv(Cs*PROJD, 256), 256, 0, stream>>>(w_q, w_kv, w_qpts, w_kvpts, Wcat);
    k_transposeW<<<dim3(PROJD/32, Cs/32), 256, 0, stream>>>(Wcat, WcatT, Cs, PROJD);
    k_transposeW<<<dim3(Cs/32, CATD/32), 256, 0, stream>>>(w_out, w_outT, CATD, Cs);
    k_transposeW<<<dim3(Cs/32, Cs/32), 256, 0, stream>>>(w_t1, w_t1T, Cs, Cs);
    k_transposeW<<<dim3(Cs/32, Cs/32), 256, 0, stream>>>(w_t2, w_t2T, Cs, Cs);
    k_transposeW<<<dim3(Cs/32, Cs/32), 256, 0, stream>>>(w_t3, w_t3T, Cs, Cs);
    k_bproj<<<Nres*Nres/16, 256, 0, stream>>>(z, w_b, b_hij_bf);
    k_zT<<<dim3(Nres, Nres/32, Cz/32), 256, 0, stream>>>(z, zTbf);

    for (int it = 0; it < NBLK; it++) {
        // projT = (s @ Wcat)^T  (512 x 384 x 1152), full-K, transposed fp32 write
        k_gemm_proj<<<dim3(PROJD/64, Nres/32), 256, 0, stream>>>(s_bf, WcatT, projT, Nres, Cs, PROJD);
        // point transforms + augmented QK factors + V staging
        k_prep<<<gdiv(NH*Nres, 256), 256, 0, stream>>>(projT, Rbuf, tbuf, hw, Aaug, Baug, vhTbf);
        // fused attention v2: 384 blocks, direct-global fragments
        k_attn<<<dim3(Nres/16, NH), 256, 0, stream>>>(Aaug, Baug, b_hij_bf, vhTbf, Rbuf, tbuf, Pbf, cat_bf);
        // o_pair via MFMA against pre-transposed bf16 z
        k_opair<<<Nres, 256, 0, stream>>>(Pbf, zTbf, cat_bf);
        // s += cat @ w_out + b_out  (512 x 2112 x 384), split-K=6, then fused LN1
        k_gemm_mfma<<<dim3(Cs/64, Nres/64, 6), 256, 0, stream>>>(cat_bf, w_outT, Pslab, Nres, CATD, Cs, 352);
        k_reduce_ln<<<Nres, Cs, 0, stream>>>(Pslab, b_out, s_cur, s_bf, ln1_g, ln1_b, 6);
        // transitions: split-K=2, reduce+relu fused into consumer A-staging
        k_gemm_tr<<<dim3(Cs/64, Nres/32, 2), 256, 0, stream>>>(s_bf, nullptr, nullptr, w_t1T, Pslab, 0);
        k_gemm_tr<<<dim3(Cs/64, Nres/32, 2), 256, 0, stream>>>(nullptr, Pslab, Pslab + MNs, w_t2T, Pslab + 2*MNs, 1);
        k_gemm_tr<<<dim3(Cs/64, Nres/32, 2), 256, 0, stream>>>(nullptr, Pslab + 2*MNs, Pslab + 3*MNs, w_t3T, Pslab + 4*MNs, 1);
        // fused: residual add + LN2 + backbone update (+ final pack on last iter)
        k_reduce_ln_bb<<<Nres, Cs, 0, stream>>>(Pslab + 4*MNs, s_cur, s_bf, ln2_g, ln2_b, 2,
                                                w_bb, b_bb, Rbuf, tbuf,
                                                (it == NBLK - 1) ? out : nullptr);
    }
}